// Round 18
// baseline (75.889 us; speedup 1.0000x reference)
//
#include <hip/hip_runtime.h>

typedef unsigned short u16;
typedef __attribute__((ext_vector_type(4))) float f32x4;
typedef __attribute__((ext_vector_type(8))) short bf16x8;
typedef __attribute__((ext_vector_type(4))) u16 u16x4;
typedef __attribute__((ext_vector_type(8))) u16 u16x8;

#define MFMA(a, b, c) __builtin_amdgcn_mfma_f32_16x16x32_bf16(a, b, c, 0, 0, 0)

__device__ __forceinline__ u16 f2bf(float f) {
    unsigned u = __float_as_uint(f);
    u += 0x7fffu + ((u >> 16) & 1u);   // round-to-nearest-even
    return (u16)(u >> 16);
}
__device__ __forceinline__ float bf2f(u16 h) {
    unsigned u = ((unsigned)h) << 16;
    return __uint_as_float(u);
}

__device__ __forceinline__ void load_lds16(const void* g, void* l) {
    __builtin_amdgcn_global_load_lds((const __attribute__((address_space(1))) void*)g,
                                     (__attribute__((address_space(3))) void*)l,
                                     16, 0, 0);
}

// ---------------------------------------------------------------------------
// Kernel 1: pack Wq|Wk|Wv (fp32 [1024][64]) -> Wt2 bf16 col-major-K:
// Wt2[col][k], col 0..191 (q|k|v), k 0..1023. Coalesced 8B writes.
// ---------------------------------------------------------------------------
__global__ __launch_bounds__(256) void wt_pack(const float* __restrict__ Wq,
                                               const float* __restrict__ Wk,
                                               const float* __restrict__ Wv,
                                               u16* __restrict__ Wt2) {
    const int n = blockIdx.x;        // 0..191
    const int t = threadIdx.x;       // 0..255
    const float* W = (n < 64) ? Wq : (n < 128 ? Wk : Wv);
    const int c = n & 63;
    u16x4 pk;
#pragma unroll
    for (int i = 0; i < 4; ++i) pk[i] = f2bf(W[(size_t)(t * 4 + i) * 64 + c]);
    *(u16x4*)&Wt2[(size_t)n * 1024 + t * 4] = pk;
}

// ---------------------------------------------------------------------------
// Kernel 2: qkv projection with REGISTER-RESIDENT B (no Wt staging at all).
// 12 waves (768 thr), wave owns 16 output cols; B-frags for a 512-K pass
// live in 16 bf16x8 (64 VGPR), loaded once per pass by plain global loads
// (L2-resident, ~25MB total vs 192MB re-staged). LDS stages ONLY x:
// 8KB/K-step dbuf (16KB). BM=32, grid 512. Staged bytes: 64MB (was 256MB).
// Q pre-scaled by log2(e)/sqrt(1024).
// ---------------------------------------------------------------------------
__global__ __launch_bounds__(768, 3) void qkv_gemm(const float* __restrict__ x,
                                                   const u16* __restrict__ Wt2,
                                                   u16* __restrict__ qo,
                                                   u16* __restrict__ ko,
                                                   u16* __restrict__ vT) {
    const int tid = threadIdx.x;
    const int lane = tid & 63, wave = tid >> 6;   // 12 waves
    const int lr = lane & 15, lg = lane >> 4;
    const int m0 = blockIdx.x * 32;
    const int colg = wave * 16 + lr;              // global output col 0..191

    __shared__ __align__(16) float xs[2][32 * 64];   // 8KB each

    f32x4 acc[2];
    acc[0] = (f32x4){0.f, 0.f, 0.f, 0.f};
    acc[1] = (f32x4){0.f, 0.f, 0.f, 0.f};

    // x staging: 512 chunks of 16B; waves 0..7 stage (wave-uniform guard).
#define QSTAGE(bufi, kg_)                                                              \
    if (tid < 512) {                                                                   \
        const int row = tid >> 4, cc = tid & 15;                                       \
        load_lds16(x + (size_t)(m0 + row) * 1024 + (kg_)*64 + ((cc ^ (row & 7)) << 2), \
                   &xs[bufi][wave * 256]);                                             \
    }

    QSTAGE(0, 0);
    __syncthreads();

    const u16* wcol = Wt2 + (size_t)colg * 1024 + lg * 8;

#pragma unroll
    for (int p = 0; p < 2; ++p) {
        // ---- B-frags for this 512-K pass: 16 x 16B plain loads, reg-resident.
        bf16x8 bfr[8][2];
#pragma unroll
        for (int kt = 0; kt < 8; ++kt)
#pragma unroll
            for (int h = 0; h < 2; ++h)
                bfr[kt][h] = *(const bf16x8*)(wcol + p * 512 + kt * 64 + h * 32);

#pragma unroll
        for (int kt = 0; kt < 8; ++kt) {
            const int kg = p * 8 + kt;
            const int cur = kg & 1;
            if (kg < 15) QSTAGE(cur ^ 1, kg + 1);

#pragma unroll
            for (int h = 0; h < 2; ++h) {
#pragma unroll
                for (int mm = 0; mm < 2; ++mm) {
                    const int rr = mm * 16 + lr;
                    const int c0 = h * 8 + lg * 2;
                    f32x4 f0 = *(const f32x4*)&xs[cur][rr * 64 + ((c0 ^ (rr & 7)) << 2)];
                    f32x4 f1 = *(const f32x4*)&xs[cur][rr * 64 + (((c0 + 1) ^ (rr & 7)) << 2)];
                    bf16x8 a;
#pragma unroll
                    for (int i = 0; i < 4; ++i) {
                        a[i] = (short)f2bf(f0[i]);
                        a[i + 4] = (short)f2bf(f1[i]);
                    }
                    acc[mm] = MFMA(a, bfr[kt][h], acc[mm]);
                }
            }
            __syncthreads();
        }
    }

    // ---- epilogue: D col = colg (lane lr), row = m0 + mm*16 + lg*4 + r
    const float SCQ = 0.0450842200277801f;   // log2(e)/sqrt(1024)
    const int bb = m0 >> 11;
    const int tb = m0 & 2047;
    if (colg < 64) {
#pragma unroll
        for (int mm = 0; mm < 2; ++mm)
#pragma unroll
            for (int r = 0; r < 4; ++r)
                qo[(size_t)(m0 + mm * 16 + lg * 4 + r) * 64 + colg] =
                    f2bf(acc[mm][r] * SCQ);
    } else if (colg < 128) {
#pragma unroll
        for (int mm = 0; mm < 2; ++mm)
#pragma unroll
            for (int r = 0; r < 4; ++r)
                ko[(size_t)(m0 + mm * 16 + lg * 4 + r) * 64 + (colg - 64)] =
                    f2bf(acc[mm][r]);
    } else {
#pragma unroll
        for (int mm = 0; mm < 2; ++mm) {
            u16x4 pk;
#pragma unroll
            for (int r = 0; r < 4; ++r) pk[r] = f2bf(acc[mm][r]);
            *(u16x4*)&vT[(size_t)(bb * 64 + (colg - 128)) * 2048 + tb + mm * 16 + lg * 4] = pk;
        }
    }
}

// ---------------------------------------------------------------------------
// Kernel 3: causal attention — R13 structure + s_setprio (best known).
// ---------------------------------------------------------------------------
#define PPITCH 72
__global__ __launch_bounds__(256, 3) void attn_part(const u16* __restrict__ q,
                                                    const u16* __restrict__ k,
                                                    const u16* __restrict__ vT,
                                                    u16* __restrict__ Opb,
                                                    float* __restrict__ Lp) {
    const int b = blockIdx.x & 7;
    int g = blockIdx.x >> 3;                  // 0..79, heavy-first
    int qt = 31, rem = g;
    while (rem >= (qt >> 3) + 1) { rem -= (qt >> 3) + 1; --qt; }
    const int c0 = rem;
    const int q0 = qt * 64;
    const int kv_lo = c0 * 512;
    const int kv_hi = min(kv_lo + 512, q0 + 64);
    const int ntiles = (kv_hi - kv_lo) >> 6;
    const int slot = (b * 32 + qt) * 4 + c0;

    __shared__ __align__(16) u16 lK[2][64 * 64];     // 8KB each
    __shared__ __align__(16) u16 lV[2][64 * 64];     // 8KB each
    __shared__ __align__(16) u16 lP[4][16 * PPITCH]; // per-wave P

    const int tid = threadIdx.x;
    const int wave = tid >> 6, lane = tid & 63;
    const int lr = lane & 15, lg = lane >> 4;

    const u16* qb = q + (size_t)b * 2048 * 64;
    const u16* kb = k + (size_t)b * 2048 * 64;
    const u16* vb = vT + (size_t)b * 64 * 2048;

    const int myrow = q0 + wave * 16 + lr;
    const bf16x8 qf0 = *(const bf16x8*)(qb + (size_t)myrow * 64 + lg * 8);
    const bf16x8 qf1 = *(const bf16x8*)(qb + (size_t)myrow * 64 + 32 + lg * 8);

    f32x4 oacc[4];
#pragma unroll
    for (int n = 0; n < 4; ++n) oacc[n] = (f32x4){0.f, 0.f, 0.f, 0.f};
    float rs = 0.f;

#define ASTAGE(bufi, kv0_)                                                             \
    {                                                                                  \
        _Pragma("unroll") for (int j = 0; j < 2; ++j) {                                \
            const int cid = j * 256 + wave * 64 + lane;                                \
            const int row = cid >> 3, cc = cid & 7;                                    \
            load_lds16(kb + (size_t)((kv0_) + row) * 64 + ((cc ^ (row & 7)) << 3),     \
                       &lK[bufi][(j * 256 + wave * 64) * 8]);                          \
            load_lds16(vb + (size_t)row * 2048 + (kv0_) + ((cc ^ (row & 7)) << 3),     \
                       &lV[bufi][(j * 256 + wave * 64) * 8]);                          \
        }                                                                              \
    }

    ASTAGE(0, kv_lo);
    __syncthreads();

    for (int it = 0; it < ntiles; ++it) {
        const int cur = it & 1;
        if (it + 1 < ntiles) ASTAGE(cur ^ 1, kv_lo + (it + 1) * 64);

        const int kv0 = kv_lo + it * 64;
        if (kv0 <= q0 + wave * 16 + 15) {      // wave-uniform causal guard
            f32x4 s[4];
            __builtin_amdgcn_s_setprio(1);
#pragma unroll
            for (int n = 0; n < 4; ++n) {
                const int row = n * 16 + lr;
                const bf16x8 kf0 = *(const bf16x8*)&lK[cur][row * 64 + ((lg ^ (row & 7)) << 3)];
                const bf16x8 kf1 =
                    *(const bf16x8*)&lK[cur][row * 64 + (((4 + lg) ^ (row & 7)) << 3)];
                f32x4 a = (f32x4){0.f, 0.f, 0.f, 0.f};
                a = MFMA(kf0, qf0, a);
                a = MFMA(kf1, qf1, a);
                s[n] = a;   // S^T: rows kv = 16n+lg*4+r, col q = lr
            }
            __builtin_amdgcn_s_setprio(0);

            const bool msk = (kv0 + 63 > q0 + wave * 16);
#pragma unroll
            for (int n = 0; n < 4; ++n) {
                u16x4 pk;
#pragma unroll
                for (int r = 0; r < 4; ++r) {
                    const int kvi = kv0 + n * 16 + lg * 4 + r;
                    const float p = (!msk || kvi <= myrow) ? exp2f(s[n][r]) : 0.f;
                    rs += p;
                    pk[r] = f2bf(p);
                }
                *(u16x4*)&lP[wave][lr * PPITCH + n * 16 + lg * 4] = pk;
            }

            __builtin_amdgcn_s_setprio(1);
#pragma unroll
            for (int kc = 0; kc < 2; ++kc) {
                const bf16x8 pf = *(const bf16x8*)&lP[wave][lr * PPITCH + kc * 32 + lg * 8];
#pragma unroll
                for (int n = 0; n < 4; ++n) {
                    const int row = n * 16 + lr;
                    const bf16x8 vf =
                        *(const bf16x8*)&lV[cur][row * 64 + (((kc * 4 + lg) ^ (row & 7)) << 3)];
                    oacc[n] = MFMA(pf, vf, oacc[n]);
                }
            }
            __builtin_amdgcn_s_setprio(0);
        }
        __syncthreads();
    }

    // ---- row-sum across the 4 lanes sharing lr
    rs += __shfl_xor(rs, 16);
    rs += __shfl_xor(rs, 32);
    if (lane < 16) Lp[slot * 64 + wave * 16 + lr] = rs;

    // ---- bf16 partials, MFMA-native layout
    u16* op = Opb + (size_t)slot * 4096 + wave * 1024;
#pragma unroll
    for (int n = 0; n < 4; ++n)
#pragma unroll
        for (int r = 0; r < 4; ++r)
            op[n * 256 + (lg * 4 + r) * 16 + lr] = f2bf(oacc[n][r]);
}

// ---------------------------------------------------------------------------
// Kernel 4: vectorized merge (unchanged from R13).
// ---------------------------------------------------------------------------
__global__ __launch_bounds__(256) void attn_combine(const u16* __restrict__ Opb,
                                                    const float* __restrict__ Lp,
                                                    float* __restrict__ out) {
    const int gid = blockIdx.x * 256 + threadIdx.x;   // 131072
    const int colg = gid & 7;
    const int row = gid >> 3;            // b*2048 + t
    const int b = row >> 11, tt = row & 2047;
    const int qt = tt >> 6, i = tt & 63;
    const int nc = (qt >> 3) + 1;
    const size_t sbase = (size_t)(b * 32 + qt) * 4;
    const int sub0 = (i >> 4) * 1024 + (colg >> 1) * 256 + (i & 15) * 16 + (colg & 1) * 8;

    float O[8] = {0.f, 0.f, 0.f, 0.f, 0.f, 0.f, 0.f, 0.f};
    float L = 0.f;
    for (int c = 0; c < nc; ++c) {
        const u16x8 v = *(const u16x8*)&Opb[(sbase + c) * 4096 + sub0];
#pragma unroll
        for (int j = 0; j < 8; ++j) O[j] += bf2f(v[j]);
        L += Lp[(sbase + c) * 64 + i];
    }
    const float rinv = 1.0f / L;
    f32x4 o0, o1;
#pragma unroll
    for (int j = 0; j < 4; ++j) {
        o0[j] = O[j] * rinv;
        o1[j] = O[4 + j] * rinv;
    }
    float* ob = out + (size_t)row * 64 + colg * 8;
    *(f32x4*)(ob) = o0;
    *(f32x4*)(ob + 4) = o1;
}

// ---------------------------------------------------------------------------
extern "C" void kernel_launch(void* const* d_in, const int* in_sizes, int n_in,
                              void* d_out, int out_size, void* d_ws, size_t ws_size,
                              hipStream_t stream) {
    const float* x = (const float*)d_in[0];
    const float* Wq = (const float*)d_in[1];
    const float* Wk = (const float*)d_in[2];
    const float* Wv = (const float*)d_in[3];
    float* out = (float*)d_out;

    char* ws = (char*)d_ws;
    u16* Wt2 = (u16*)ws;                                  // 384 KB @ 0
    u16* qb = (u16*)(ws + (512 << 10));                   // 2 MB
    u16* kb = (u16*)(ws + (512 << 10) + (2 << 20));       // 2 MB
    u16* vT = (u16*)(ws + (512 << 10) + (4 << 20));       // 2 MB
    u16* Opb = (u16*)(ws + (8 << 20));                    // 8.4 MB
    float* Lp = (float*)(ws + (20 << 20));                // 256 KB

    wt_pack<<<192, 256, 0, stream>>>(Wq, Wk, Wv, Wt2);
    qkv_gemm<<<512, 768, 0, stream>>>(x, Wt2, qb, kb, vT);
    attn_part<<<640, 256, 0, stream>>>(qb, kb, vT, Opb, Lp);
    attn_combine<<<512, 256, 0, stream>>>(Opb, Lp, out);
}

// Round 20
// 65.852 us; speedup vs baseline: 1.1524x; 1.1524x over previous
//
#include <hip/hip_runtime.h>

typedef unsigned short u16;
typedef __attribute__((ext_vector_type(4))) float f32x4;
typedef __attribute__((ext_vector_type(8))) short bf16x8;
typedef __attribute__((ext_vector_type(4))) u16 u16x4;
typedef __attribute__((ext_vector_type(8))) u16 u16x8;

#define MFMA(a, b, c) __builtin_amdgcn_mfma_f32_16x16x32_bf16(a, b, c, 0, 0, 0)

__device__ __forceinline__ u16 f2bf(float f) {
    unsigned u = __float_as_uint(f);
    u += 0x7fffu + ((u >> 16) & 1u);   // round-to-nearest-even
    return (u16)(u >> 16);
}
__device__ __forceinline__ float bf2f(u16 h) {
    unsigned u = ((unsigned)h) << 16;
    return __uint_as_float(u);
}

__device__ __forceinline__ void load_lds16(const void* g, void* l) {
    __builtin_amdgcn_global_load_lds((const __attribute__((address_space(1))) void*)g,
                                     (__attribute__((address_space(3))) void*)l,
                                     16, 0, 0);
}

// ---------------------------------------------------------------------------
// Kernel 1: pack Wq|Wk|Wv (fp32 [1024][64]) -> Wtt bf16 in per-kc chunks:
// Wtt[((kc*192 + n)*16 + cs)*8 + ci], kc=k>>7, c=(k&127)>>3, ci=k&7,
// cs = (c&8)|((c&7)^(n&7))  (XOR swizzle baked in; chunk stages linearly).
// ---------------------------------------------------------------------------
__global__ void wt_pack(const float* __restrict__ Wq, const float* __restrict__ Wk,
                        const float* __restrict__ Wv, u16* __restrict__ Wtt) {
    const int k = blockIdx.x;        // 0..1023
    const int n = threadIdx.x;       // 0..191
    const float* W = (n < 64) ? Wq : (n < 128 ? Wk : Wv);
    const float v = W[(size_t)k * 64 + (n & 63)];
    const int kc = k >> 7, kl = k & 127, c = kl >> 3, ci = kl & 7;
    const int cs = (c & 8) | ((c & 7) ^ (n & 7));
    Wtt[((size_t)(kc * 192 + n) * 16 + cs) * 8 + ci] = f2bf(v);
}

// ---------------------------------------------------------------------------
// Kernel 2: split-K persistent-W qkv GEMM. Block = (kc = bid&7, mb = bid>>3).
// Wt K-chunk [192][128] bf16 = 48KB loaded into LDS ONCE (staged 24MB total
// device-wide vs 192MB before). x staged once (64MB, K-sliced). Per m-tile
// (BM=32): 16KB staged, 96 MFMA, ONE barrier pair (6 MFMA/KB). LDS 80KB ->
// 2 blocks/CU, grid 512 fully resident. bf16 partials to Pp[kc][16384][192].
// ---------------------------------------------------------------------------
__global__ __launch_bounds__(256, 2) void qkv_gemm(const float* __restrict__ x,
                                                   const u16* __restrict__ Wtt,
                                                   u16* __restrict__ Pp) {
    const int tid = threadIdx.x;
    const int lane = tid & 63, wave = tid >> 6;
    const int lr = lane & 15, lg = lane >> 4;
    const int wc = wave;                      // wave owns 48 output cols
    const int kc = blockIdx.x & 7;
    const int mb = blockIdx.x >> 3;           // 0..63, 256 rows each

    __shared__ __align__(16) u16 wsm[192 * 128];     // 48KB, static
    __shared__ __align__(16) float xs[2][32 * 128];  // 16KB each

    // ---- load W chunk once: 3072 16B-chunks, 12/thread, linear dest
#pragma unroll
    for (int j = 0; j < 12; ++j) {
        const int cid = j * 256 + tid;
        load_lds16(Wtt + (size_t)kc * 24576 + cid * 8, &wsm[(j * 256 + wave * 64) * 8]);
    }

    // x stage: 1024 chunks (32 rows x 32 chunks), 4/thread, inverse-swizzled src
#define XSTAGE(bufi, mrow_)                                                            \
    {                                                                                  \
        _Pragma("unroll") for (int j = 0; j < 4; ++j) {                                \
            const int cid = j * 256 + tid;                                             \
            const int row = cid >> 5, cch = cid & 31;                                  \
            const int csw = (cch & 0x18) | ((cch & 7) ^ (row & 7));                    \
            load_lds16(x + (size_t)((mrow_) + row) * 1024 + kc * 128 + (csw << 2),     \
                       &xs[bufi][(j * 256 + wave * 64) * 4]);                          \
        }                                                                              \
    }

    XSTAGE(0, mb * 256);
    __syncthreads();

    for (int mi = 0; mi < 8; ++mi) {
        const int cur = mi & 1;
        if (mi < 7) XSTAGE(cur ^ 1, mb * 256 + (mi + 1) * 32);

        f32x4 acc[2][3];
#pragma unroll
        for (int m = 0; m < 2; ++m)
#pragma unroll
            for (int n = 0; n < 3; ++n) acc[m][n] = (f32x4){0.f, 0.f, 0.f, 0.f};

#pragma unroll
        for (int ks = 0; ks < 4; ++ks) {
            bf16x8 a[2];
#pragma unroll
            for (int mm = 0; mm < 2; ++mm) {
                const int rr = mm * 16 + lr;
                const int c0 = ks * 8 + lg * 2;
                const int cs0 = (ks * 8) | ((lg * 2) ^ (rr & 7));
                const int cs1 = (ks * 8) | ((lg * 2 + 1) ^ (rr & 7));
                (void)c0;
                f32x4 f0 = *(const f32x4*)&xs[cur][rr * 128 + cs0 * 4];
                f32x4 f1 = *(const f32x4*)&xs[cur][rr * 128 + cs1 * 4];
                bf16x8 t;
#pragma unroll
                for (int i = 0; i < 4; ++i) {
                    t[i] = (short)f2bf(f0[i]);
                    t[i + 4] = (short)f2bf(f1[i]);
                }
                a[mm] = t;
            }
#pragma unroll
            for (int nl = 0; nl < 3; ++nl) {
                const int row = wc * 48 + nl * 16 + lr;
                const int cb = ks * 4 + lg;
                const int cs = (cb & 8) | ((cb & 7) ^ (row & 7));
                const bf16x8 b = *(const bf16x8*)&wsm[row * 128 + cs * 8];
                acc[0][nl] = MFMA(a[0], b, acc[0][nl]);
                acc[1][nl] = MFMA(a[1], b, acc[1][nl]);
            }
        }

        // ---- write bf16 partials for this m-tile
        const int mrow = mb * 256 + mi * 32;
        u16* pp = Pp + (size_t)kc * 3145728;
#pragma unroll
        for (int mm = 0; mm < 2; ++mm)
#pragma unroll
            for (int nl = 0; nl < 3; ++nl) {
                const int col = wc * 48 + nl * 16 + lr;
#pragma unroll
                for (int r = 0; r < 4; ++r)
                    pp[(size_t)(mrow + mm * 16 + lg * 4 + r) * 192 + col] =
                        f2bf(acc[mm][nl][r]);
            }
        __syncthreads();
    }
}

// ---------------------------------------------------------------------------
// Kernel 3: merge the 8 K-chunk partials -> q (x SCQ), k, vT.
// Thread owns 8 consecutive cols of one row; 8x u16x8 loads (L3-resident).
// ---------------------------------------------------------------------------
__global__ __launch_bounds__(256) void qkv_combine(const u16* __restrict__ Pp,
                                                   u16* __restrict__ qo,
                                                   u16* __restrict__ ko,
                                                   u16* __restrict__ vT) {
    const int gid = blockIdx.x * 256 + threadIdx.x;   // 393216
    const int row = gid / 24;
    const int col0 = (gid % 24) * 8;

    float O[8] = {0.f, 0.f, 0.f, 0.f, 0.f, 0.f, 0.f, 0.f};
#pragma unroll
    for (int kc = 0; kc < 8; ++kc) {
        const u16x8 v = *(const u16x8*)&Pp[(size_t)kc * 3145728 + (size_t)row * 192 + col0];
#pragma unroll
        for (int j = 0; j < 8; ++j) O[j] += bf2f(v[j]);
    }

    const float SCQ = 0.0450842200277801f;   // log2(e)/sqrt(1024)
    if (col0 < 64) {
        u16x8 pk;
#pragma unroll
        for (int j = 0; j < 8; ++j) pk[j] = f2bf(O[j] * SCQ);
        *(u16x8*)&qo[(size_t)row * 64 + col0] = pk;
    } else if (col0 < 128) {
        u16x8 pk;
#pragma unroll
        for (int j = 0; j < 8; ++j) pk[j] = f2bf(O[j]);
        *(u16x8*)&ko[(size_t)row * 64 + (col0 - 64)] = pk;
    } else {
        const int bb = row >> 11, t = row & 2047;
#pragma unroll
        for (int j = 0; j < 8; ++j)
            vT[(size_t)(bb * 64 + col0 - 128 + j) * 2048 + t] = f2bf(O[j]);
    }
}

// ---------------------------------------------------------------------------
// Kernel 4: causal attention — R13 structure + s_setprio (best known).
// ---------------------------------------------------------------------------
#define PPITCH 72
__global__ __launch_bounds__(256, 3) void attn_part(const u16* __restrict__ q,
                                                    const u16* __restrict__ k,
                                                    const u16* __restrict__ vT,
                                                    u16* __restrict__ Opb,
                                                    float* __restrict__ Lp) {
    const int b = blockIdx.x & 7;
    int g = blockIdx.x >> 3;                  // 0..79, heavy-first
    int qt = 31, rem = g;
    while (rem >= (qt >> 3) + 1) { rem -= (qt >> 3) + 1; --qt; }
    const int c0 = rem;
    const int q0 = qt * 64;
    const int kv_lo = c0 * 512;
    const int kv_hi = min(kv_lo + 512, q0 + 64);
    const int ntiles = (kv_hi - kv_lo) >> 6;
    const int slot = (b * 32 + qt) * 4 + c0;

    __shared__ __align__(16) u16 lK[2][64 * 64];     // 8KB each
    __shared__ __align__(16) u16 lV[2][64 * 64];     // 8KB each
    __shared__ __align__(16) u16 lP[4][16 * PPITCH]; // per-wave P

    const int tid = threadIdx.x;
    const int wave = tid >> 6, lane = tid & 63;
    const int lr = lane & 15, lg = lane >> 4;

    const u16* qb = q + (size_t)b * 2048 * 64;
    const u16* kb = k + (size_t)b * 2048 * 64;
    const u16* vb = vT + (size_t)b * 64 * 2048;

    const int myrow = q0 + wave * 16 + lr;
    const bf16x8 qf0 = *(const bf16x8*)(qb + (size_t)myrow * 64 + lg * 8);
    const bf16x8 qf1 = *(const bf16x8*)(qb + (size_t)myrow * 64 + 32 + lg * 8);

    f32x4 oacc[4];
#pragma unroll
    for (int n = 0; n < 4; ++n) oacc[n] = (f32x4){0.f, 0.f, 0.f, 0.f};
    float rs = 0.f;

#define ASTAGE(bufi, kv0_)                                                             \
    {                                                                                  \
        _Pragma("unroll") for (int j = 0; j < 2; ++j) {                                \
            const int cid = j * 256 + wave * 64 + lane;                                \
            const int row = cid >> 3, cc = cid & 7;                                    \
            load_lds16(kb + (size_t)((kv0_) + row) * 64 + ((cc ^ (row & 7)) << 3),     \
                       &lK[bufi][(j * 256 + wave * 64) * 8]);                          \
            load_lds16(vb + (size_t)row * 2048 + (kv0_) + ((cc ^ (row & 7)) << 3),     \
                       &lV[bufi][(j * 256 + wave * 64) * 8]);                          \
        }                                                                              \
    }

    ASTAGE(0, kv_lo);
    __syncthreads();

    for (int it = 0; it < ntiles; ++it) {
        const int cur = it & 1;
        if (it + 1 < ntiles) ASTAGE(cur ^ 1, kv_lo + (it + 1) * 64);

        const int kv0 = kv_lo + it * 64;
        if (kv0 <= q0 + wave * 16 + 15) {      // wave-uniform causal guard
            f32x4 s[4];
            __builtin_amdgcn_s_setprio(1);
#pragma unroll
            for (int n = 0; n < 4; ++n) {
                const int row = n * 16 + lr;
                const bf16x8 kf0 = *(const bf16x8*)&lK[cur][row * 64 + ((lg ^ (row & 7)) << 3)];
                const bf16x8 kf1 =
                    *(const bf16x8*)&lK[cur][row * 64 + (((4 + lg) ^ (row & 7)) << 3)];
                f32x4 a = (f32x4){0.f, 0.f, 0.f, 0.f};
                a = MFMA(kf0, qf0, a);
                a = MFMA(kf1, qf1, a);
                s[n] = a;   // S^T: rows kv = 16n+lg*4+r, col q = lr
            }
            __builtin_amdgcn_s_setprio(0);

            const bool msk = (kv0 + 63 > q0 + wave * 16);
#pragma unroll
            for (int n = 0; n < 4; ++n) {
                u16x4 pk;
#pragma unroll
                for (int r = 0; r < 4; ++r) {
                    const int kvi = kv0 + n * 16 + lg * 4 + r;
                    const float p = (!msk || kvi <= myrow) ? exp2f(s[n][r]) : 0.f;
                    rs += p;
                    pk[r] = f2bf(p);
                }
                *(u16x4*)&lP[wave][lr * PPITCH + n * 16 + lg * 4] = pk;
            }

            __builtin_amdgcn_s_setprio(1);
#pragma unroll
            for (int kc = 0; kc < 2; ++kc) {
                const bf16x8 pf = *(const bf16x8*)&lP[wave][lr * PPITCH + kc * 32 + lg * 8];
#pragma unroll
                for (int n = 0; n < 4; ++n) {
                    const int row = n * 16 + lr;
                    const bf16x8 vf =
                        *(const bf16x8*)&lV[cur][row * 64 + (((kc * 4 + lg) ^ (row & 7)) << 3)];
                    oacc[n] = MFMA(pf, vf, oacc[n]);
                }
            }
            __builtin_amdgcn_s_setprio(0);
        }
        __syncthreads();
    }

    // ---- row-sum across the 4 lanes sharing lr
    rs += __shfl_xor(rs, 16);
    rs += __shfl_xor(rs, 32);
    if (lane < 16) Lp[slot * 64 + wave * 16 + lr] = rs;

    // ---- bf16 partials, MFMA-native layout
    u16* op = Opb + (size_t)slot * 4096 + wave * 1024;
#pragma unroll
    for (int n = 0; n < 4; ++n)
#pragma unroll
        for (int r = 0; r < 4; ++r)
            op[n * 256 + (lg * 4 + r) * 16 + lr] = f2bf(oacc[n][r]);
}

// ---------------------------------------------------------------------------
// Kernel 5: vectorized attn merge (unchanged).
// ---------------------------------------------------------------------------
__global__ __launch_bounds__(256) void attn_combine(const u16* __restrict__ Opb,
                                                    const float* __restrict__ Lp,
                                                    float* __restrict__ out) {
    const int gid = blockIdx.x * 256 + threadIdx.x;   // 131072
    const int colg = gid & 7;
    const int row = gid >> 3;            // b*2048 + t
    const int b = row >> 11, tt = row & 2047;
    const int qt = tt >> 6, i = tt & 63;
    const int nc = (qt >> 3) + 1;
    const size_t sbase = (size_t)(b * 32 + qt) * 4;
    const int sub0 = (i >> 4) * 1024 + (colg >> 1) * 256 + (i & 15) * 16 + (colg & 1) * 8;

    float O[8] = {0.f, 0.f, 0.f, 0.f, 0.f, 0.f, 0.f, 0.f};
    float L = 0.f;
    for (int c = 0; c < nc; ++c) {
        const u16x8 v = *(const u16x8*)&Opb[(sbase + c) * 4096 + sub0];
#pragma unroll
        for (int j = 0; j < 8; ++j) O[j] += bf2f(v[j]);
        L += Lp[(sbase + c) * 64 + i];
    }
    const float rinv = 1.0f / L;
    f32x4 o0, o1;
#pragma unroll
    for (int j = 0; j < 4; ++j) {
        o0[j] = O[j] * rinv;
        o1[j] = O[4 + j] * rinv;
    }
    float* ob = out + (size_t)row * 64 + colg * 8;
    *(f32x4*)(ob) = o0;
    *(f32x4*)(ob + 4) = o1;
}

// ---------------------------------------------------------------------------
extern "C" void kernel_launch(void* const* d_in, const int* in_sizes, int n_in,
                              void* d_out, int out_size, void* d_ws, size_t ws_size,
                              hipStream_t stream) {
    const float* x = (const float*)d_in[0];
    const float* Wq = (const float*)d_in[1];
    const float* Wk = (const float*)d_in[2];
    const float* Wv = (const float*)d_in[3];
    float* out = (float*)d_out;

    char* ws = (char*)d_ws;
    u16* Wtt = (u16*)ws;                                  // 384 KB @ 0
    u16* qb = (u16*)(ws + (512 << 10));                   // 2 MB
    u16* kb = (u16*)(ws + (512 << 10) + (2 << 20));       // 2 MB
    u16* vT = (u16*)(ws + (512 << 10) + (4 << 20));       // 2 MB
    // shared region @6.5M: Pp (12.6MB, dies after qkv_combine) aliases Opb (8.4MB)
    u16* Pp = (u16*)(ws + ((13 << 20) >> 1));             // 6.5 MB
    u16* Opb = (u16*)(ws + ((13 << 20) >> 1));            // same base (aliased)
    float* Lp = (float*)(ws + (20 << 20));                // 256 KB

    wt_pack<<<1024, 192, 0, stream>>>(Wq, Wk, Wv, Wtt);
    qkv_gemm<<<512, 256, 0, stream>>>(x, Wtt, Pp);
    qkv_combine<<<1536, 256, 0, stream>>>(Pp, qb, kb, vT);
    attn_part<<<640, 256, 0, stream>>>(qb, kb, vT, Opb, Lp);
    attn_combine<<<512, 256, 0, stream>>>(Opb, Lp, out);
}

// Round 21
// 54.881 us; speedup vs baseline: 1.3828x; 1.1999x over previous
//
#include <hip/hip_runtime.h>

typedef unsigned short u16;
typedef __attribute__((ext_vector_type(4))) float f32x4;
typedef __attribute__((ext_vector_type(8))) short bf16x8;
typedef __attribute__((ext_vector_type(4))) u16 u16x4;
typedef __attribute__((ext_vector_type(8))) u16 u16x8;

#define MFMA(a, b, c) __builtin_amdgcn_mfma_f32_16x16x32_bf16(a, b, c, 0, 0, 0)

__device__ __forceinline__ u16 f2bf(float f) {
    unsigned u = __float_as_uint(f);
    u += 0x7fffu + ((u >> 16) & 1u);   // round-to-nearest-even
    return (u16)(u >> 16);
}
__device__ __forceinline__ float bf2f(u16 h) {
    unsigned u = ((unsigned)h) << 16;
    return __uint_as_float(u);
}

__device__ __forceinline__ void load_lds16(const void* g, void* l) {
    __builtin_amdgcn_global_load_lds((const __attribute__((address_space(1))) void*)g,
                                     (__attribute__((address_space(3))) void*)l,
                                     16, 0, 0);
}

// ---------------------------------------------------------------------------
// Kernel 1: pack Wq|Wk|Wv (fp32 [1024][64]) -> Wtt bf16, tile-major + swizzled
// (R13-exact): Wtt[kt*12288 + n*64 + ((c^(n&7))<<3)+ci].
// ---------------------------------------------------------------------------
__global__ void wt_pack(const float* __restrict__ Wq, const float* __restrict__ Wk,
                        const float* __restrict__ Wv, u16* __restrict__ Wtt) {
    const int k = blockIdx.x;        // 0..1023
    const int n = threadIdx.x;       // 0..191
    const float* W = (n < 64) ? Wq : (n < 128 ? Wk : Wv);
    const float v = W[(size_t)k * 64 + (n & 63)];
    const int kt = k >> 6, ks = k & 63, c = ks >> 3, ci = ks & 7;
    Wtt[(size_t)kt * 12288 + n * 64 + (((c ^ (n & 7)) << 3) + ci)] = f2bf(v);
}

// ---------------------------------------------------------------------------
// Kernel 2: qkv projection, m97-structure, BM=32 / 4 waves / 512 blocks
// (R13-exact — verified local optimum: 2 blocks/CU cross-block overlap).
// Q output pre-scaled by log2(e)/sqrt(1024).
// ---------------------------------------------------------------------------
__global__ __launch_bounds__(256, 2) void qkv_gemm(const float* __restrict__ x,
                                                   const u16* __restrict__ Wtt,
                                                   u16* __restrict__ qo,
                                                   u16* __restrict__ ko,
                                                   u16* __restrict__ vT) {
    const int tid = threadIdx.x;
    const int lane = tid & 63, wave = tid >> 6;
    const int lr = lane & 15, lg = lane >> 4;
    const int m0 = blockIdx.x * 32;

    __shared__ __align__(16) float xs[2][32 * 64];
    __shared__ __align__(16) u16 ws[2][192 * 64];

    f32x4 acc[2][3];
#pragma unroll
    for (int m = 0; m < 2; ++m)
#pragma unroll
        for (int n = 0; n < 3; ++n) acc[m][n] = (f32x4){0.f, 0.f, 0.f, 0.f};

    const int srow = tid >> 4;
    const int schk = tid & 15;

    {
#pragma unroll
        for (int j = 0; j < 2; ++j) {
            const int rr = j * 16 + srow;
            const float* src = x + (size_t)(m0 + rr) * 1024 + ((schk ^ (rr & 7)) << 2);
            load_lds16(src, &xs[0][j * 1024 + wave * 256]);
        }
#pragma unroll
        for (int j = 0; j < 6; ++j) {
            const u16* src = Wtt + (size_t)j * 2048 + tid * 8;
            load_lds16(src, &ws[0][j * 2048 + wave * 512]);
        }
    }
    __syncthreads();

    for (int kt = 0; kt < 16; ++kt) {
        const int cur = kt & 1;
        if (kt < 15) {
            const int nxt = cur ^ 1;
#pragma unroll
            for (int j = 0; j < 2; ++j) {
                const int rr = j * 16 + srow;
                const float* src =
                    x + (size_t)(m0 + rr) * 1024 + (kt + 1) * 64 + ((schk ^ (rr & 7)) << 2);
                load_lds16(src, &xs[nxt][j * 1024 + wave * 256]);
            }
#pragma unroll
            for (int j = 0; j < 6; ++j) {
                const u16* src = Wtt + (size_t)(kt + 1) * 12288 + j * 2048 + tid * 8;
                load_lds16(src, &ws[nxt][j * 2048 + wave * 512]);
            }
        }
#pragma unroll
        for (int h = 0; h < 2; ++h) {
            bf16x8 a[2];
#pragma unroll
            for (int mm = 0; mm < 2; ++mm) {
                const int rr = mm * 16 + lr;
                const int c0 = h * 8 + lg * 2;
                f32x4 f0 = *(const f32x4*)&xs[cur][rr * 64 + ((c0 ^ (rr & 7)) << 2)];
                f32x4 f1 = *(const f32x4*)&xs[cur][rr * 64 + (((c0 + 1) ^ (rr & 7)) << 2)];
                bf16x8 t;
#pragma unroll
                for (int i = 0; i < 4; ++i) {
                    t[i] = (short)f2bf(f0[i]);
                    t[i + 4] = (short)f2bf(f1[i]);
                }
                a[mm] = t;
            }
#pragma unroll
            for (int nl = 0; nl < 3; ++nl) {
                const int row = (wave * 3 + nl) * 16 + lr;
                const int cb = h * 4 + lg;
                const bf16x8 b = *(const bf16x8*)&ws[cur][row * 64 + ((cb ^ (row & 7)) << 3)];
                acc[0][nl] = MFMA(a[0], b, acc[0][nl]);
                acc[1][nl] = MFMA(a[1], b, acc[1][nl]);
            }
        }
        __syncthreads();
    }

    const float SCQ = 0.0450842200277801f;   // log2(e)/sqrt(1024)
    const int bb = m0 >> 11;
    const int tb = m0 & 2047;
#pragma unroll
    for (int mm = 0; mm < 2; ++mm)
#pragma unroll
        for (int nl = 0; nl < 3; ++nl) {
            const int col = (wave * 3 + nl) * 16 + lr;
            const int rl = mm * 16 + lg * 4;
            if (col < 64) {
#pragma unroll
                for (int r = 0; r < 4; ++r)
                    qo[(size_t)(m0 + rl + r) * 64 + col] = f2bf(acc[mm][nl][r] * SCQ);
            } else if (col < 128) {
#pragma unroll
                for (int r = 0; r < 4; ++r)
                    ko[(size_t)(m0 + rl + r) * 64 + (col - 64)] = f2bf(acc[mm][nl][r]);
            } else {
                u16x4 pk;
#pragma unroll
                for (int r = 0; r < 4; ++r) pk[r] = f2bf(acc[mm][nl][r]);
                *(u16x4*)&vT[(size_t)(bb * 64 + (col - 128)) * 2048 + tb + rl] = pk;
            }
        }
}

// ---------------------------------------------------------------------------
// Kernel 3: causal attention — R13 structure + s_setprio around MFMA clusters
// (T5; the ONLY change vs the 54.99us R13 baseline).
// ---------------------------------------------------------------------------
#define PPITCH 72
__global__ __launch_bounds__(256, 3) void attn_part(const u16* __restrict__ q,
                                                    const u16* __restrict__ k,
                                                    const u16* __restrict__ vT,
                                                    u16* __restrict__ Opb,
                                                    float* __restrict__ Lp) {
    const int b = blockIdx.x & 7;
    int g = blockIdx.x >> 3;                  // 0..79, heavy-first
    int qt = 31, rem = g;
    while (rem >= (qt >> 3) + 1) { rem -= (qt >> 3) + 1; --qt; }
    const int c0 = rem;
    const int q0 = qt * 64;
    const int kv_lo = c0 * 512;
    const int kv_hi = min(kv_lo + 512, q0 + 64);
    const int ntiles = (kv_hi - kv_lo) >> 6;
    const int slot = (b * 32 + qt) * 4 + c0;

    __shared__ __align__(16) u16 lK[2][64 * 64];     // 8KB each
    __shared__ __align__(16) u16 lV[2][64 * 64];     // 8KB each
    __shared__ __align__(16) u16 lP[4][16 * PPITCH]; // per-wave P

    const int tid = threadIdx.x;
    const int wave = tid >> 6, lane = tid & 63;
    const int lr = lane & 15, lg = lane >> 4;

    const u16* qb = q + (size_t)b * 2048 * 64;
    const u16* kb = k + (size_t)b * 2048 * 64;
    const u16* vb = vT + (size_t)b * 64 * 2048;

    const int myrow = q0 + wave * 16 + lr;
    const bf16x8 qf0 = *(const bf16x8*)(qb + (size_t)myrow * 64 + lg * 8);
    const bf16x8 qf1 = *(const bf16x8*)(qb + (size_t)myrow * 64 + 32 + lg * 8);

    f32x4 oacc[4];
#pragma unroll
    for (int n = 0; n < 4; ++n) oacc[n] = (f32x4){0.f, 0.f, 0.f, 0.f};
    float rs = 0.f;

#define ASTAGE(bufi, kv0_)                                                             \
    {                                                                                  \
        _Pragma("unroll") for (int j = 0; j < 2; ++j) {                                \
            const int cid = j * 256 + wave * 64 + lane;                                \
            const int row = cid >> 3, cc = cid & 7;                                    \
            load_lds16(kb + (size_t)((kv0_) + row) * 64 + ((cc ^ (row & 7)) << 3),     \
                       &lK[bufi][(j * 256 + wave * 64) * 8]);                          \
            load_lds16(vb + (size_t)row * 2048 + (kv0_) + ((cc ^ (row & 7)) << 3),     \
                       &lV[bufi][(j * 256 + wave * 64) * 8]);                          \
        }                                                                              \
    }

    ASTAGE(0, kv_lo);
    __syncthreads();

    for (int it = 0; it < ntiles; ++it) {
        const int cur = it & 1;
        if (it + 1 < ntiles) ASTAGE(cur ^ 1, kv_lo + (it + 1) * 64);

        const int kv0 = kv_lo + it * 64;
        if (kv0 <= q0 + wave * 16 + 15) {      // wave-uniform causal guard
            f32x4 s[4];
            __builtin_amdgcn_s_setprio(1);
#pragma unroll
            for (int n = 0; n < 4; ++n) {
                const int row = n * 16 + lr;
                const bf16x8 kf0 = *(const bf16x8*)&lK[cur][row * 64 + ((lg ^ (row & 7)) << 3)];
                const bf16x8 kf1 =
                    *(const bf16x8*)&lK[cur][row * 64 + (((4 + lg) ^ (row & 7)) << 3)];
                f32x4 a = (f32x4){0.f, 0.f, 0.f, 0.f};
                a = MFMA(kf0, qf0, a);
                a = MFMA(kf1, qf1, a);
                s[n] = a;   // S^T: rows kv = 16n+lg*4+r, col q = lr
            }
            __builtin_amdgcn_s_setprio(0);

            const bool msk = (kv0 + 63 > q0 + wave * 16);
#pragma unroll
            for (int n = 0; n < 4; ++n) {
                u16x4 pk;
#pragma unroll
                for (int r = 0; r < 4; ++r) {
                    const int kvi = kv0 + n * 16 + lg * 4 + r;
                    const float p = (!msk || kvi <= myrow) ? exp2f(s[n][r]) : 0.f;
                    rs += p;
                    pk[r] = f2bf(p);
                }
                *(u16x4*)&lP[wave][lr * PPITCH + n * 16 + lg * 4] = pk;
            }

            __builtin_amdgcn_s_setprio(1);
#pragma unroll
            for (int kc = 0; kc < 2; ++kc) {
                const bf16x8 pf = *(const bf16x8*)&lP[wave][lr * PPITCH + kc * 32 + lg * 8];
#pragma unroll
                for (int n = 0; n < 4; ++n) {
                    const int row = n * 16 + lr;
                    const bf16x8 vf =
                        *(const bf16x8*)&lV[cur][row * 64 + (((kc * 4 + lg) ^ (row & 7)) << 3)];
                    oacc[n] = MFMA(pf, vf, oacc[n]);
                }
            }
            __builtin_amdgcn_s_setprio(0);
        }
        __syncthreads();
    }

    // ---- row-sum across the 4 lanes sharing lr
    rs += __shfl_xor(rs, 16);
    rs += __shfl_xor(rs, 32);
    if (lane < 16) Lp[slot * 64 + wave * 16 + lr] = rs;

    // ---- bf16 partials, MFMA-native layout
    u16* op = Opb + (size_t)slot * 4096 + wave * 1024;
#pragma unroll
    for (int n = 0; n < 4; ++n)
#pragma unroll
        for (int r = 0; r < 4; ++r)
            op[n * 256 + (lg * 4 + r) * 16 + lr] = f2bf(oacc[n][r]);
}

// ---------------------------------------------------------------------------
// Kernel 4: vectorized merge (R13-exact).
// ---------------------------------------------------------------------------
__global__ __launch_bounds__(256) void attn_combine(const u16* __restrict__ Opb,
                                                    const float* __restrict__ Lp,
                                                    float* __restrict__ out) {
    const int gid = blockIdx.x * 256 + threadIdx.x;   // 131072
    const int colg = gid & 7;
    const int row = gid >> 3;            // b*2048 + t
    const int b = row >> 11, tt = row & 2047;
    const int qt = tt >> 6, i = tt & 63;
    const int nc = (qt >> 3) + 1;
    const size_t sbase = (size_t)(b * 32 + qt) * 4;
    const int sub0 = (i >> 4) * 1024 + (colg >> 1) * 256 + (i & 15) * 16 + (colg & 1) * 8;

    float O[8] = {0.f, 0.f, 0.f, 0.f, 0.f, 0.f, 0.f, 0.f};
    float L = 0.f;
    for (int c = 0; c < nc; ++c) {
        const u16x8 v = *(const u16x8*)&Opb[(sbase + c) * 4096 + sub0];
#pragma unroll
        for (int j = 0; j < 8; ++j) O[j] += bf2f(v[j]);
        L += Lp[(sbase + c) * 64 + i];
    }
    const float rinv = 1.0f / L;
    f32x4 o0, o1;
#pragma unroll
    for (int j = 0; j < 4; ++j) {
        o0[j] = O[j] * rinv;
        o1[j] = O[4 + j] * rinv;
    }
    float* ob = out + (size_t)row * 64 + colg * 8;
    *(f32x4*)(ob) = o0;
    *(f32x4*)(ob + 4) = o1;
}

// ---------------------------------------------------------------------------
extern "C" void kernel_launch(void* const* d_in, const int* in_sizes, int n_in,
                              void* d_out, int out_size, void* d_ws, size_t ws_size,
                              hipStream_t stream) {
    const float* x = (const float*)d_in[0];
    const float* Wq = (const float*)d_in[1];
    const float* Wk = (const float*)d_in[2];
    const float* Wv = (const float*)d_in[3];
    float* out = (float*)d_out;

    char* ws = (char*)d_ws;
    u16* Wtt = (u16*)ws;                                  // 384 KB @ 0
    u16* qb = (u16*)(ws + (512 << 10));                   // 2 MB
    u16* kb = (u16*)(ws + (512 << 10) + (2 << 20));       // 2 MB
    u16* vT = (u16*)(ws + (512 << 10) + (4 << 20));       // 2 MB
    u16* Opb = (u16*)(ws + (8 << 20));                    // 8.4 MB
    float* Lp = (float*)(ws + (20 << 20));                // 256 KB

    wt_pack<<<1024, 192, 0, stream>>>(Wq, Wk, Wv, Wtt);
    qkv_gemm<<<512, 256, 0, stream>>>(x, Wtt, qb, kb, vT);
    attn_part<<<640, 256, 0, stream>>>(qb, kb, vT, Opb, Lp);
    attn_combine<<<512, 256, 0, stream>>>(Opb, Lp, out);
}